// Round 1
// baseline (473.681 us; speedup 1.0000x reference)
//
#include <hip/hip_runtime.h>
#include <hip/hip_cooperative_groups.h>

namespace cg = cooperative_groups;

#define SCAN_THREADS 256
#define EPT 8
#define CHUNK (SCAN_THREADS * EPT)   // 2048 elements per scan chunk
#define COOP_BLOCKS 1024             // __launch_bounds__(256,4) -> 4 blocks/CU * 256 CUs

typedef int   v4i __attribute__((ext_vector_type(4)));
typedef float v4f __attribute__((ext_vector_type(4)));

// ---------------------------------------------------------------------------
// K1: filtered = residues * sigmoid(attrs @ w + b); scatter +/- into delta.
// tpre u tpost is a permutation of [0,2N) -> every slot written exactly once.
__global__ void k1_filter_scatter(const float* __restrict__ attrs,
                                  const float* __restrict__ weight,
                                  const float* __restrict__ bias,
                                  const float* __restrict__ residues,
                                  const int* __restrict__ tpre,
                                  const int* __restrict__ tpost,
                                  float* __restrict__ delta,
                                  int N) {
    int u0 = (blockIdx.x * blockDim.x + threadIdx.x) * 2;
    v4f w0 = *(const v4f*)weight;
    v4f w1 = *(const v4f*)(weight + 4);
    float b = bias[0];
    if (u0 + 2 <= N) {
        float r0 = residues[u0], r1 = residues[u0 + 1];
        int pre0 = tpre[u0],  pre1 = tpre[u0 + 1];
        int pos0 = tpost[u0], pos1 = tpost[u0 + 1];
        v4f a00 = *(const v4f*)(attrs + (size_t)u0 * 8);
        v4f a01 = *(const v4f*)(attrs + (size_t)u0 * 8 + 4);
        v4f a10 = *(const v4f*)(attrs + (size_t)u0 * 8 + 8);
        v4f a11 = *(const v4f*)(attrs + (size_t)u0 * 8 + 12);
        float l0 = a00.x*w0.x + a00.y*w0.y + a00.z*w0.z + a00.w*w0.w +
                   a01.x*w1.x + a01.y*w1.y + a01.z*w1.z + a01.w*w1.w + b;
        float l1 = a10.x*w0.x + a10.y*w0.y + a10.z*w0.z + a10.w*w0.w +
                   a11.x*w1.x + a11.y*w1.y + a11.z*w1.z + a11.w*w1.w + b;
        float f0 = r0 / (1.0f + __expf(-l0));
        float f1 = r1 / (1.0f + __expf(-l1));
        delta[pre0] =  f0; delta[pre1] =  f1;
        delta[pos0] = -f0; delta[pos1] = -f1;
    } else {
        for (int u = u0; u < N; ++u) {
            float logit = b;
            #pragma unroll
            for (int k = 0; k < 8; ++k) logit += attrs[(size_t)u * 8 + k] * weight[k];
            float f = residues[u] / (1.0f + __expf(-logit));
            delta[tpre[u]]  =  f;
            delta[tpost[u]] = -f;
        }
    }
}

// ---------------------------------------------------------------------------
// Fused cooperative kernel: (P1) chunk partial sums, (P2) in-place chunk scan
// with self-derived offsets, (P3) vnode[u] = ycum[tpre[u]], (P4) pixel gather.
// 3 grid.sync() replace 3 kernel boundaries. Chunk<->block mapping identical
// in P1/P2 so delta chunks stay in the same XCD's L2 across the sync.
__global__ __launch_bounds__(SCAN_THREADS, 4)
void k_fused(float* __restrict__ delta,       // [T] scatter result -> becomes ycum
             float* __restrict__ partials,    // [numChunks]
             float* __restrict__ vnode,       // [N]
             const int* __restrict__ tpre,
             const int* __restrict__ nop,
             float* __restrict__ out,
             int N, int T, int P, int numChunks)
{
    cg::grid_group grid = cg::this_grid();
    __shared__ float smem[8];
    const int tid  = threadIdx.x;
    const int lane = tid & 63, wid = tid >> 6;

    // ---- Phase 1: per-chunk partial sums ----
    for (int cch = blockIdx.x; cch < numChunks; cch += gridDim.x) {
        int base = cch * CHUNK + tid * EPT;
        float s = 0.0f;
        if (base + EPT <= T) {
            v4f v0 = *(const v4f*)(delta + base);
            v4f v1 = *(const v4f*)(delta + base + 4);
            s = v0.x + v0.y + v0.z + v0.w + v1.x + v1.y + v1.z + v1.w;
        } else {
            for (int i = 0; i < EPT; ++i)
                if (base + i < T) s += delta[base + i];
        }
        #pragma unroll
        for (int d = 32; d > 0; d >>= 1) s += __shfl_down(s, d, 64);
        if (lane == 0) smem[wid] = s;
        __syncthreads();
        if (tid == 0) partials[cch] = smem[0] + smem[1] + smem[2] + smem[3];
        __syncthreads();
    }
    grid.sync();

    // ---- Phase 2: scan each chunk in place; offset = sum partials[0..c) ----
    for (int cch = blockIdx.x; cch < numChunks; cch += gridDim.x) {
        float c = 0.0f;
        for (int i = tid; i < cch; i += SCAN_THREADS) c += partials[i];
        #pragma unroll
        for (int d = 32; d > 0; d >>= 1) c += __shfl_down(c, d, 64);
        if (lane == 0) smem[4 + wid] = c;

        int base = cch * CHUNK + tid * EPT;
        float v[EPT];
        bool full = (base + EPT <= T);
        if (full) {
            v4f v0 = *(const v4f*)(delta + base);
            v4f v1 = *(const v4f*)(delta + base + 4);
            v[0]=v0.x; v[1]=v0.y; v[2]=v0.z; v[3]=v0.w;
            v[4]=v1.x; v[5]=v1.y; v[6]=v1.z; v[7]=v1.w;
        } else {
            for (int i = 0; i < EPT; ++i)
                v[i] = (base + i < T) ? delta[base + i] : 0.0f;
        }
        float run = 0.0f;
        #pragma unroll
        for (int i = 0; i < EPT; ++i) { run += v[i]; v[i] = run; }
        float tot = run;
        float x = tot;
        #pragma unroll
        for (int d = 1; d < 64; d <<= 1) {
            float y = __shfl_up(x, d, 64);
            if (lane >= d) x += y;
        }
        if (lane == 63) smem[wid] = x;
        __syncthreads();
        float woff = 0.0f, offset = smem[4] + smem[5] + smem[6] + smem[7];
        #pragma unroll
        for (int i = 0; i < SCAN_THREADS / 64; ++i)
            if (i < wid) woff += smem[i];
        float add = (x - tot) + woff + offset;
        if (full) {
            v4f o0 = { v[0]+add, v[1]+add, v[2]+add, v[3]+add };
            v4f o1 = { v[4]+add, v[5]+add, v[6]+add, v[7]+add };
            *(v4f*)(delta + base)     = o0;
            *(v4f*)(delta + base + 4) = o1;
        } else {
            for (int i = 0; i < EPT; ++i)
                if (base + i < T) delta[base + i] = v[i] + add;
        }
        __syncthreads();
    }
    grid.sync();

    // ---- Phase 3: vnode[u] = ycum[tpre[u]] ----
    {
        int u0 = (blockIdx.x * SCAN_THREADS + tid) * 2;
        if (u0 + 2 <= N) {
            int t0 = tpre[u0], t1 = tpre[u0 + 1];
            float y0 = delta[t0], y1 = delta[t1];
            vnode[u0] = y0; vnode[u0 + 1] = y1;
        } else {
            for (int u = u0; u < N; ++u) vnode[u] = delta[tpre[u]];
        }
    }
    grid.sync();

    // ---- Phase 4: out[i] = vnode[nop[i]], nt-hints keep vnode L2-resident ----
    {
        const int stride8 = gridDim.x * SCAN_THREADS * 8;
        for (int i = (blockIdx.x * SCAN_THREADS + tid) * 8; i < P; i += stride8) {
            if (i + 8 <= P) {
                v4i n0 = __builtin_nontemporal_load((const v4i*)(nop + i));
                v4i n1 = __builtin_nontemporal_load((const v4i*)(nop + i + 4));
                v4f o0 = { vnode[n0.x], vnode[n0.y], vnode[n0.z], vnode[n0.w] };
                v4f o1 = { vnode[n1.x], vnode[n1.y], vnode[n1.z], vnode[n1.w] };
                __builtin_nontemporal_store(o0, (v4f*)(out + i));
                __builtin_nontemporal_store(o1, (v4f*)(out + i + 4));
            } else {
                for (int j = i; j < P; ++j) out[j] = vnode[nop[j]];
            }
        }
    }
}

// ---------------------------------------------------------------------------
// Tiny-workspace fallback path (unchanged from previous version).
__global__ void k2_partials(const float* __restrict__ delta,
                            float* __restrict__ partials, int T) {
    __shared__ float sdata[SCAN_THREADS / 64];
    int base = blockIdx.x * CHUNK + threadIdx.x * EPT;
    float s = 0.0f;
    if (base + EPT <= T) {
        v4f v0 = *(const v4f*)(delta + base);
        v4f v1 = *(const v4f*)(delta + base + 4);
        s = v0.x + v0.y + v0.z + v0.w + v1.x + v1.y + v1.z + v1.w;
    } else {
        for (int i = 0; i < EPT; ++i)
            if (base + i < T) s += delta[base + i];
    }
    #pragma unroll
    for (int d = 32; d > 0; d >>= 1) s += __shfl_down(s, d, 64);
    int lane = threadIdx.x & 63, wid = threadIdx.x >> 6;
    if (lane == 0) sdata[wid] = s;
    __syncthreads();
    if (threadIdx.x == 0)
        partials[blockIdx.x] = sdata[0] + sdata[1] + sdata[2] + sdata[3];
}

__global__ void k4_scan_chunks(float* __restrict__ data,
                               const float* __restrict__ partials, int T) {
    __shared__ float wavesums[SCAN_THREADS / 64];
    __shared__ float redsum[SCAN_THREADS / 64];
    int lane = threadIdx.x & 63, wid = threadIdx.x >> 6;
    float c = 0.0f;
    for (int i = threadIdx.x; i < blockIdx.x; i += SCAN_THREADS)
        c += partials[i];
    #pragma unroll
    for (int d = 32; d > 0; d >>= 1) c += __shfl_down(c, d, 64);
    if (lane == 0) redsum[wid] = c;

    int base = blockIdx.x * CHUNK + threadIdx.x * EPT;
    float v[EPT];
    bool full = (base + EPT <= T);
    if (full) {
        v4f v0 = *(const v4f*)(data + base);
        v4f v1 = *(const v4f*)(data + base + 4);
        v[0]=v0.x; v[1]=v0.y; v[2]=v0.z; v[3]=v0.w;
        v[4]=v1.x; v[5]=v1.y; v[6]=v1.z; v[7]=v1.w;
    } else {
        for (int i = 0; i < EPT; ++i)
            v[i] = (base + i < T) ? data[base + i] : 0.0f;
    }
    float run = 0.0f;
    #pragma unroll
    for (int i = 0; i < EPT; ++i) { run += v[i]; v[i] = run; }
    float tot = run;
    float x = tot;
    #pragma unroll
    for (int d = 1; d < 64; d <<= 1) {
        float y = __shfl_up(x, d, 64);
        if (lane >= d) x += y;
    }
    if (lane == 63) wavesums[wid] = x;
    __syncthreads();
    float woff = 0.0f, offset = redsum[0] + redsum[1] + redsum[2] + redsum[3];
    #pragma unroll
    for (int i = 0; i < SCAN_THREADS / 64; ++i)
        if (i < wid) woff += wavesums[i];
    float add = (x - tot) + woff + offset;
    if (full) {
        v4f o0 = { v[0]+add, v[1]+add, v[2]+add, v[3]+add };
        v4f o1 = { v[4]+add, v[5]+add, v[6]+add, v[7]+add };
        *(v4f*)(data + base)     = o0;
        *(v4f*)(data + base + 4) = o1;
    } else {
        for (int i = 0; i < EPT; ++i)
            if (base + i < T) data[base + i] = v[i] + add;
    }
}

__global__ void k6_direct(const float* __restrict__ ycum,
                          const int* __restrict__ tpre,
                          const int* __restrict__ nop,
                          float* __restrict__ out, int P) {
    int i = (blockIdx.x * blockDim.x + threadIdx.x) * 4;
    if (i + 4 <= P) {
        v4i n = *(const v4i*)(nop + i);
        v4f o = { ycum[tpre[n.x]], ycum[tpre[n.y]], ycum[tpre[n.z]], ycum[tpre[n.w]] };
        *(v4f*)(out + i) = o;
    } else {
        for (; i < P; ++i) out[i] = ycum[tpre[nop[i]]];
    }
}

extern "C" void kernel_launch(void* const* d_in, const int* in_sizes, int n_in,
                              void* d_out, int out_size, void* d_ws, size_t ws_size,
                              hipStream_t stream) {
    const float* weight   = (const float*)d_in[0];
    const float* bias     = (const float*)d_in[1];
    const float* residues = (const float*)d_in[2];
    const float* attrs    = (const float*)d_in[3];
    const int*   tpre     = (const int*)d_in[4];
    const int*   tpost    = (const int*)d_in[5];
    const int*   nop      = (const int*)d_in[6];
    float* out = (float*)d_out;

    const int N = in_sizes[2];        // 500,000
    const int T = 2 * N;              // 1,000,000
    const int P = out_size;           // 8,388,608
    const int numChunks = (T + CHUNK - 1) / CHUNK;   // 489

    size_t needFull = (size_t)(T + N + 1024) * sizeof(float);
    size_t needMid  = (size_t)(N + 1024) * sizeof(float);

    float* delta;
    float* vnode    = nullptr;
    float* partials;
    int tier;

    if (ws_size >= needFull) {
        delta    = (float*)d_ws;
        vnode    = delta + T;
        partials = vnode + N;
        tier = 2;
    } else if (ws_size >= needMid) {
        delta    = out;               // dead until phase 4 rewrites it fully
        vnode    = (float*)d_ws;
        partials = vnode + N;
        tier = 1;
    } else {
        delta    = out;
        partials = (float*)d_ws;
        tier = 0;
    }

    k1_filter_scatter<<<(N / 2 + 255) / 256, 256, 0, stream>>>(
        attrs, weight, bias, residues, tpre, tpost, delta, N);

    if (tier >= 1) {
        float* deltaArg = delta;
        float* partialsArg = partials;
        float* vnodeArg = vnode;
        const int* tpreArg = tpre;
        const int* nopArg = nop;
        float* outArg = out;
        int nN = N, nT = T, nP = P, nC = numChunks;
        void* args[] = { &deltaArg, &partialsArg, &vnodeArg, &tpreArg, &nopArg,
                         &outArg, &nN, &nT, &nP, &nC };
        hipLaunchCooperativeKernel(k_fused, dim3(COOP_BLOCKS), dim3(SCAN_THREADS),
                                   args, 0, stream);
    } else {
        k2_partials<<<numChunks, SCAN_THREADS, 0, stream>>>(delta, partials, T);
        k4_scan_chunks<<<numChunks, SCAN_THREADS, 0, stream>>>(delta, partials, T);
        int gatherBlocks = (P / 4 + 255) / 256;
        k6_direct<<<gatherBlocks, 256, 0, stream>>>(delta, tpre, nop, out, P);
    }
}